// Round 11
// baseline (73.599 us; speedup 1.0000x reference)
//
#include <hip/hip_runtime.h>

#define NB   16
#define CINC 32
#define HH   128
#define WWD  128
#define FF   32
#define OPSN 5
#define EPSV 1e-5f

// ws layout:
//   floats [0:1024)        acc: 16 copies x [sum[32] | sumsq[32]]  (zeroed by K1)
//   floats [1024:2048)     acc2: dummy accumulator for measurement replicas
//   bytes  at 262400       wfrag (18 frags * 64 lanes * 8 bf16 = 18432 B)
//   bytes  at 280832       xt  [16][130][130][32] bf16
#define WS_WFRAG_BOFF   262400
#define WS_XT_BOFF      280832
#define WS_NEED         (280832 + (size_t)16*130*130*32*2)

typedef __attribute__((ext_vector_type(8))) short bf16x8;
typedef __attribute__((ext_vector_type(4))) float f32x4;

__device__ __forceinline__ unsigned short f2bf(float f) {
    unsigned u = __builtin_bit_cast(unsigned, f);
    u += 0x7FFFu + ((u >> 16) & 1u);
    return (unsigned short)(u >> 16);
}
__device__ __forceinline__ unsigned pack2(float lo, float hi) {
    return (unsigned)f2bf(lo) | ((unsigned)f2bf(hi) << 16);
}

// ---------------------------------------------------------------------------
// K1 transform (identical to R10)
// ---------------------------------------------------------------------------
__global__ __launch_bounds__(256) void transform_kernel(
    const float* __restrict__ x, const float* __restrict__ Wall,
    const int* __restrict__ opidx, unsigned short* __restrict__ xt,
    unsigned short* __restrict__ wfrag, float* __restrict__ acc)
{
    __shared__ float lds[128 * 35];
    const int bid = blockIdx.x;
    const int tid = threadIdx.x;

    if (bid == NB * 130) {
        for (int i = tid; i < 1024; i += 256) acc[i] = 0.f;
        for (int idx = tid; idx < 9216; idx += 256) {
            int frag = idx >> 9;          // 0..17
            int lane = (idx >> 3) & 63;
            int j    = idx & 7;
            int s = frag >> 1, m = frag & 1;
            int kh = s / 3, kw = s - 3 * kh;
            int f = m * 16 + (lane & 15);
            int c = ((lane >> 4) << 3) + j;
            float v = Wall[((size_t)(f * OPSN + opidx[f]) * 288) + c * 9 + kh * 3 + kw];
            wfrag[idx] = f2bf(v);
        }
        return;
    }

    const int idx = bid >> 3;                      // 0..259
    const int n   = (bid & 7) * 2 + (idx / 130);   // XCD-aligned n
    const int hp  = idx % 130;

    unsigned short* rowp = xt + (size_t)(n * 130 + hp) * 130 * 32;
    uint4 zz = make_uint4(0, 0, 0, 0);

    if (hp == 0 || hp == 129) {
        for (int c = tid; c < 520; c += 256) ((uint4*)rowp)[c] = zz;
        return;
    }

    const int h = hp - 1;
    const float* xr = x + ((size_t)n * CINC * HH + h) * WWD;
    const int c  = tid >> 3;
    const int wq = tid & 7;
#pragma unroll
    for (int it = 0; it < 4; ++it) {
        int w4 = wq + it * 8;
        float4 v = ((const float4*)(xr + (size_t)c * (HH * WWD)))[w4];
        int w = w4 * 4;
        lds[(w + 0) * 35 + c] = v.x;
        lds[(w + 1) * 35 + c] = v.y;
        lds[(w + 2) * 35 + c] = v.z;
        lds[(w + 3) * 35 + c] = v.w;
    }
    __syncthreads();
    for (int cc = tid; cc < 512; cc += 256) {
        int p = cc >> 2, k = cc & 3;
        const float* s = &lds[p * 35 + k * 8];
        uint4 o;
        o.x = pack2(s[0], s[1]); o.y = pack2(s[2], s[3]);
        o.z = pack2(s[4], s[5]); o.w = pack2(s[6], s[7]);
        ((uint4*)rowp)[4 + cc] = o;
    }
    if (tid < 4)       ((uint4*)rowp)[tid] = zz;
    else if (tid < 8)  ((uint4*)rowp)[129 * 4 + tid - 4] = zz;
}

// -------- rolling-row conv helpers (identical to R10) -----------------------
#define LOADROW(f0, f1, f2, R)                                                  \
    {                                                                           \
        const unsigned short* rp =                                              \
            xbase + ((size_t)(R) * 130 + w0) * 32 + laneoff;                    \
        f0 = *(const bf16x8*)(rp);                                              \
        f1 = *(const bf16x8*)(rp + 32);                                         \
        f2 = *(const bf16x8*)(rp + 64);                                         \
    }

#define MROW(f0, f1, f2, aA, aB, kh)                                            \
    {                                                                           \
        aA = __builtin_amdgcn_mfma_f32_16x16x32_bf16(wfr[2*((kh)*3+0)],   f0, aA, 0,0,0); \
        aB = __builtin_amdgcn_mfma_f32_16x16x32_bf16(wfr[2*((kh)*3+0)+1], f0, aB, 0,0,0); \
        aA = __builtin_amdgcn_mfma_f32_16x16x32_bf16(wfr[2*((kh)*3+1)],   f1, aA, 0,0,0); \
        aB = __builtin_amdgcn_mfma_f32_16x16x32_bf16(wfr[2*((kh)*3+1)+1], f1, aB, 0,0,0); \
        aA = __builtin_amdgcn_mfma_f32_16x16x32_bf16(wfr[2*((kh)*3+2)],   f2, aA, 0,0,0); \
        aB = __builtin_amdgcn_mfma_f32_16x16x32_bf16(wfr[2*((kh)*3+2)+1], f2, aB, 0,0,0); \
    }

#define CONV_PROLOGUE                                                           \
    bf16x8 wfr[18];                                                             \
    _Pragma("unroll")                                                           \
    for (int i = 0; i < 18; ++i)                                                \
        wfr[i] = *(const bf16x8*)(wfrag + (i * 64 + lane) * 8);                 \
    const unsigned short* xbase = xt + (size_t)n * 130 * 130 * 32;              \
    const int laneoff = l15 * 32 + lhi * 8;                                     \
    f32x4 zz4 = {0.f, 0.f, 0.f, 0.f};                                           \
    f32x4 a0A = zz4, a0B = zz4, a1A = zz4, a1B = zz4;                           \
    f32x4 a2A = zz4, a2B = zz4, a3A = zz4, a3B = zz4;                           \
    bf16x8 c0, c1, c2, n0, n1, n2;                                              \
    LOADROW(c0, c1, c2, h0);                                                    \
    LOADROW(n0, n1, n2, h0 + 1);

#define CONV_BODY(FIN)                                                          \
    MROW(c0, c1, c2, a0A, a0B, 0);                                              \
    LOADROW(c0, c1, c2, h0 + 2);                                                \
    MROW(n0, n1, n2, a0A, a0B, 1);                                              \
    MROW(n0, n1, n2, a1A, a1B, 0);                                              \
    LOADROW(n0, n1, n2, h0 + 3);                                                \
    MROW(c0, c1, c2, a0A, a0B, 2);                                              \
    MROW(c0, c1, c2, a1A, a1B, 1);                                              \
    MROW(c0, c1, c2, a2A, a2B, 0);                                              \
    FIN(a0A, a0B, 0);                                                           \
    LOADROW(c0, c1, c2, h0 + 4);                                                \
    MROW(n0, n1, n2, a1A, a1B, 2);                                              \
    MROW(n0, n1, n2, a2A, a2B, 1);                                              \
    MROW(n0, n1, n2, a3A, a3B, 0);                                              \
    FIN(a1A, a1B, 1);                                                           \
    LOADROW(n0, n1, n2, h0 + 5);                                                \
    MROW(c0, c1, c2, a2A, a2B, 2);                                              \
    MROW(c0, c1, c2, a3A, a3B, 1);                                              \
    FIN(a2A, a2B, 2);                                                           \
    MROW(n0, n1, n2, a3A, a3B, 2);                                              \
    FIN(a3A, a3B, 3);

// ---------------------------------------------------------------------------
// K2 conv_stats (identical to R10; acc pointer selects real vs dummy region)
// ---------------------------------------------------------------------------
__global__ __launch_bounds__(256) void conv_stats_kernel(
    const unsigned short* __restrict__ xt,
    const unsigned short* __restrict__ wfrag,
    float* __restrict__ acc)
{
    __shared__ float red[4][64];
    const int bid  = blockIdx.x;
    const int tid  = threadIdx.x;
    const int n    = (bid & 7) * 2 + ((bid >> 3) & 1);
    const int rest = bid >> 4;
    const int h0   = (rest & 31) * 4;
    const int wh   = rest >> 5;
    const int lane = tid & 63;
    const int wv   = tid >> 6;
    const int w0   = wh * 64 + wv * 16;
    const int l15  = lane & 15, lhi = lane >> 4;

    float s8[8], q8[8];
#pragma unroll
    for (int j = 0; j < 8; ++j) { s8[j] = 0.f; q8[j] = 0.f; }

#define FIN_STATS(aA, aB, hh)                                                   \
    {                                                                           \
        _Pragma("unroll")                                                       \
        for (int r = 0; r < 4; ++r) {                                           \
            float v0 = aA[r], v1 = aB[r];                                       \
            s8[r]     += v0;  q8[r]     += v0 * v0;                             \
            s8[4 + r] += v1;  q8[4 + r] += v1 * v1;                             \
        }                                                                       \
    }

    CONV_PROLOGUE
    CONV_BODY(FIN_STATS)
#undef FIN_STATS

#pragma unroll
    for (int m = 1; m < 16; m <<= 1) {
#pragma unroll
        for (int j = 0; j < 8; ++j) {
            s8[j] += __shfl_xor(s8[j], m, 64);
            q8[j] += __shfl_xor(q8[j], m, 64);
        }
    }
    if (l15 == 0) {
#pragma unroll
        for (int j = 0; j < 8; ++j) {
            int f = (j < 4) ? (lhi * 4 + j) : (16 + lhi * 4 + (j - 4));
            red[wv][f]      = s8[j];
            red[wv][32 + f] = q8[j];
        }
    }
    __syncthreads();
    if (tid < 64) {
        float v = red[0][tid] + red[1][tid] + red[2][tid] + red[3][tid];
        atomicAdd(&acc[n * 64 + tid], v);
    }
}

// ---------------------------------------------------------------------------
// K3 conv_apply (identical to R10)
// ---------------------------------------------------------------------------
__global__ __launch_bounds__(256) void conv_apply_kernel(
    const unsigned short* __restrict__ xt,
    const unsigned short* __restrict__ wfrag,
    const float* __restrict__ acc,
    const float* __restrict__ gamma, const float* __restrict__ beta,
    float* __restrict__ out)
{
    __shared__ float tot[64];
    __shared__ float bns[64];
    const int bid  = blockIdx.x;
    const int tid  = threadIdx.x;

    if (tid < 64) {
        float s = 0.f;
#pragma unroll
        for (int k = 0; k < 16; ++k) s += acc[k * 64 + tid];
        tot[tid] = s;
    }
    __syncthreads();
    if (tid < 32) {
        float cnt  = (float)(NB * HH * WWD);
        float mean = tot[tid] / cnt;
        float var  = tot[32 + tid] / cnt - mean * mean;
        float sc   = gamma[tid] * rsqrtf(var + EPSV);
        bns[tid]      = sc;
        bns[32 + tid] = beta[tid] - mean * sc;
    }

    const int n    = (bid & 7) * 2 + ((bid >> 3) & 1);
    const int rest = bid >> 4;
    const int h0   = (rest & 31) * 4;
    const int wh   = rest >> 5;
    const int lane = tid & 63;
    const int wv   = tid >> 6;
    const int w0   = wh * 64 + wv * 16;
    const int l15  = lane & 15, lhi = lane >> 4;

    __syncthreads();   // bns ready
    float sc0[4], sh0[4], sc1[4], sh1[4];
#pragma unroll
    for (int r = 0; r < 4; ++r) {
        int f0 = lhi * 4 + r, f1 = 16 + lhi * 4 + r;
        sc0[r] = bns[f0]; sh0[r] = bns[32 + f0];
        sc1[r] = bns[f1]; sh1[r] = bns[32 + f1];
    }

    float* ob = out + (size_t)(n * FF + lhi * 4) * (HH * WWD) + h0 * WWD + w0 + l15;

#define FIN_APPLY(aA, aB, hh)                                                   \
    {                                                                           \
        _Pragma("unroll")                                                       \
        for (int r = 0; r < 4; ++r) {                                           \
            __builtin_nontemporal_store(                                        \
                fmaxf(fmaf(aA[r], sc0[r], sh0[r]), 0.f),                        \
                ob + (size_t)r * (HH * WWD) + (hh) * WWD);                      \
            __builtin_nontemporal_store(                                        \
                fmaxf(fmaf(aB[r], sc1[r], sh1[r]), 0.f),                        \
                ob + (size_t)r * (HH * WWD) + 16 * (HH * WWD) + (hh) * WWD);    \
        }                                                                       \
    }

    CONV_PROLOGUE
    CONV_BODY(FIN_APPLY)
#undef FIN_APPLY
}

// ======================= fallback (fp32 VALU, small-ws) =====================
__global__ __launch_bounds__(256) void conv_kernel(
    const float* __restrict__ x, const float* __restrict__ Wall,
    const int* __restrict__ opidx, float* __restrict__ out)
{
    __shared__ float wlds[FF * 289];
    __shared__ float xlds[8 * 3 * 132];
    const int tid = threadIdx.x;
    const int h = blockIdx.x;
    const int n = blockIdx.y;
    for (int i = tid; i < FF * 288; i += 256) {
        int f = i / 288;
        int r = i - f * 288;
        int op = opidx[f];
        wlds[f * 289 + r] = Wall[(f * OPSN + op) * 288 + r];
    }
    const int f = tid & 31;
    const int wg = tid >> 5;
    const int w0 = wg << 4;
    float acc[16];
#pragma unroll
    for (int i = 0; i < 16; ++i) acc[i] = 0.f;
    const float* xn = x + (size_t)n * CINC * HH * WWD;
    for (int cc = 0; cc < 4; ++cc) {
        __syncthreads();
        for (int i = tid; i < 8 * 3 * 132; i += 256) {
            int c8 = i / (3 * 132);
            int rem = i - c8 * (3 * 132);
            int r = rem / 132;
            int wp = rem - r * 132;
            int hin = h + r - 1;
            int win = wp - 1;
            float v = 0.f;
            if ((unsigned)hin < HH && (unsigned)win < WWD)
                v = xn[((cc * 8 + c8) * HH + hin) * WWD + win];
            xlds[i] = v;
        }
        __syncthreads();
#pragma unroll
        for (int c8 = 0; c8 < 8; ++c8) {
            const int c = cc * 8 + c8;
            float wv[9];
#pragma unroll
            for (int k = 0; k < 9; ++k) wv[k] = wlds[f * 289 + c * 9 + k];
#pragma unroll
            for (int kh = 0; kh < 3; ++kh) {
                float xr[20];
                const float4* p = (const float4*)&xlds[(c8 * 3 + kh) * 132 + w0];
#pragma unroll
                for (int j = 0; j < 5; ++j) {
                    float4 v = p[j];
                    xr[j * 4 + 0] = v.x; xr[j * 4 + 1] = v.y;
                    xr[j * 4 + 2] = v.z; xr[j * 4 + 3] = v.w;
                }
#pragma unroll
                for (int kw = 0; kw < 3; ++kw) {
                    float wgt = wv[kh * 3 + kw];
#pragma unroll
                    for (int i = 0; i < 16; ++i)
                        acc[i] = fmaf(xr[i + kw], wgt, acc[i]);
                }
            }
        }
    }
    float* op_ = out + (((size_t)(n * FF + f) * HH + h) * WWD + w0);
#pragma unroll
    for (int j = 0; j < 4; ++j)
        ((float4*)op_)[j] = make_float4(acc[j * 4], acc[j * 4 + 1],
                                        acc[j * 4 + 2], acc[j * 4 + 3]);
}

__global__ __launch_bounds__(256) void stats_kernel(
    const float* __restrict__ out, const float* __restrict__ gamma,
    const float* __restrict__ beta, float* __restrict__ ws)
{
    __shared__ float ssum[256], ssq[256];
    const int f = blockIdx.x;
    const int tid = threadIdx.x;
    float s = 0.f, q = 0.f;
    for (int n = 0; n < NB; ++n) {
        const float4* p = (const float4*)(out + (size_t)(n * FF + f) * HH * WWD);
        for (int i = tid; i < HH * WWD / 4; i += 256) {
            float4 v = p[i];
            s += v.x + v.y + v.z + v.w;
            q += v.x * v.x + v.y * v.y + v.z * v.z + v.w * v.w;
        }
    }
    ssum[tid] = s; ssq[tid] = q;
    __syncthreads();
    for (int st = 128; st > 0; st >>= 1) {
        if (tid < st) { ssum[tid] += ssum[tid + st]; ssq[tid] += ssq[tid + st]; }
        __syncthreads();
    }
    if (tid == 0) {
        float cnt = (float)(NB * HH * WWD);
        float mean = ssum[0] / cnt;
        float var = ssq[0] / cnt - mean * mean;
        float sc = gamma[f] * rsqrtf(var + EPSV);
        ws[f] = sc;
        ws[FF + f] = beta[f] - mean * sc;
    }
}

__global__ __launch_bounds__(256) void apply_kernel(
    float* __restrict__ out, const float* __restrict__ bnp)
{
    const int total4 = NB * FF * HH * WWD / 4;
    for (int i = blockIdx.x * 256 + threadIdx.x; i < total4; i += gridDim.x * 256) {
        int f = (i >> 12) & 31;
        float sc = bnp[f], sh = bnp[FF + f];
        float4 v = ((const float4*)out)[i];
        v.x = fmaxf(fmaf(v.x, sc, sh), 0.f);
        v.y = fmaxf(fmaf(v.y, sc, sh), 0.f);
        v.z = fmaxf(fmaf(v.z, sc, sh), 0.f);
        v.w = fmaxf(fmaf(v.w, sc, sh), 0.f);
        ((float4*)out)[i] = v;
    }
}
// ===========================================================================

extern "C" void kernel_launch(void* const* d_in, const int* in_sizes, int n_in,
                              void* d_out, int out_size, void* d_ws, size_t ws_size,
                              hipStream_t stream) {
    const float* x     = (const float*)d_in[0];
    const float* Wall  = (const float*)d_in[1];
    const float* gamma = (const float*)d_in[2];
    const float* beta  = (const float*)d_in[3];
    const int*   opidx = (const int*)d_in[4];
    float* out = (float*)d_out;
    float* ws  = (float*)d_ws;

    if (ws_size >= WS_NEED) {
        float*          acc   = ws;
        float*          acc2  = ws + 1024;   // dummy target for measurement
        unsigned short* wfrag = (unsigned short*)((char*)d_ws + WS_WFRAG_BOFF);
        unsigned short* xt    = (unsigned short*)((char*)d_ws + WS_XT_BOFF);

        transform_kernel<<<NB * 130 + 1, 256, 0, stream>>>(x, Wall, opidx, xt, wfrag, acc);
        conv_stats_kernel<<<1024, 256, 0, stream>>>(xt, wfrag, acc);
        // --- measurement replicas (write dummy region; never read) ---
        conv_stats_kernel<<<1024, 256, 0, stream>>>(xt, wfrag, acc2);
        conv_stats_kernel<<<1024, 256, 0, stream>>>(xt, wfrag, acc2);
        conv_stats_kernel<<<1024, 256, 0, stream>>>(xt, wfrag, acc2);
        // --------------------------------------------------------------
        conv_apply_kernel<<<1024, 256, 0, stream>>>(xt, wfrag, acc, gamma, beta, out);
    } else {
        dim3 gridc(HH, NB);
        conv_kernel<<<gridc, 256, 0, stream>>>(x, Wall, opidx, out);
        stats_kernel<<<FF, 256, 0, stream>>>(out, gamma, beta, ws);
        apply_kernel<<<2048, 256, 0, stream>>>(out, ws);
    }
}

// Round 12
// 56.537 us; speedup vs baseline: 1.3018x; 1.3018x over previous
//
#include <hip/hip_runtime.h>

#define NB   16
#define CINC 32
#define HH   128
#define WWD  128
#define FF   32
#define OPSN 5
#define EPSV 1e-5f

// ws layout:
//   floats [0:1024)        acc: 16 copies x [sum[32] | sumsq[32]]  (zeroed by K1)
//   bytes  at 262400       wfrag (18 frags * 64 lanes * 8 bf16 = 18432 B)
//   bytes  at 280832       xt [16][130][130][32] bf16   (17,305,600 B)
//   bytes  at 17586432     co [16][32][128][128] fp16   (16,777,216 B)
#define WS_WFRAG_BOFF   262400
#define WS_XT_BOFF      280832
#define WS_CO_BOFF      17586432
#define WS_NEED         (280832 + (size_t)16*130*130*32*2)
#define WS_NEED2        (WS_CO_BOFF + (size_t)NB*FF*HH*WWD*2)

typedef __attribute__((ext_vector_type(8))) short bf16x8;
typedef __attribute__((ext_vector_type(4))) float f32x4;

__device__ __forceinline__ unsigned short f2bf(float f) {
    unsigned u = __builtin_bit_cast(unsigned, f);
    u += 0x7FFFu + ((u >> 16) & 1u);
    return (unsigned short)(u >> 16);
}
__device__ __forceinline__ unsigned pack2(float lo, float hi) {
    return (unsigned)f2bf(lo) | ((unsigned)f2bf(hi) << 16);
}
__device__ __forceinline__ unsigned short f2h(float f) {
    _Float16 h = (_Float16)f;
    return __builtin_bit_cast(unsigned short, h);
}
__device__ __forceinline__ float h2f(unsigned short u) {
    return (float)__builtin_bit_cast(_Float16, u);
}

// ---------------------------------------------------------------------------
// K1 transform (identical to R10)
// ---------------------------------------------------------------------------
__global__ __launch_bounds__(256) void transform_kernel(
    const float* __restrict__ x, const float* __restrict__ Wall,
    const int* __restrict__ opidx, unsigned short* __restrict__ xt,
    unsigned short* __restrict__ wfrag, float* __restrict__ acc)
{
    __shared__ float lds[128 * 35];
    const int bid = blockIdx.x;
    const int tid = threadIdx.x;

    if (bid == NB * 130) {
        for (int i = tid; i < 1024; i += 256) acc[i] = 0.f;
        for (int idx = tid; idx < 9216; idx += 256) {
            int frag = idx >> 9;          // 0..17
            int lane = (idx >> 3) & 63;
            int j    = idx & 7;
            int s = frag >> 1, m = frag & 1;
            int kh = s / 3, kw = s - 3 * kh;
            int f = m * 16 + (lane & 15);
            int c = ((lane >> 4) << 3) + j;
            float v = Wall[((size_t)(f * OPSN + opidx[f]) * 288) + c * 9 + kh * 3 + kw];
            wfrag[idx] = f2bf(v);
        }
        return;
    }

    const int idx = bid >> 3;                      // 0..259
    const int n   = (bid & 7) * 2 + (idx / 130);   // XCD-aligned n
    const int hp  = idx % 130;

    unsigned short* rowp = xt + (size_t)(n * 130 + hp) * 130 * 32;
    uint4 zz = make_uint4(0, 0, 0, 0);

    if (hp == 0 || hp == 129) {
        for (int c = tid; c < 520; c += 256) ((uint4*)rowp)[c] = zz;
        return;
    }

    const int h = hp - 1;
    const float* xr = x + ((size_t)n * CINC * HH + h) * WWD;
    const int c  = tid >> 3;
    const int wq = tid & 7;
#pragma unroll
    for (int it = 0; it < 4; ++it) {
        int w4 = wq + it * 8;
        float4 v = ((const float4*)(xr + (size_t)c * (HH * WWD)))[w4];
        int w = w4 * 4;
        lds[(w + 0) * 35 + c] = v.x;
        lds[(w + 1) * 35 + c] = v.y;
        lds[(w + 2) * 35 + c] = v.z;
        lds[(w + 3) * 35 + c] = v.w;
    }
    __syncthreads();
    for (int cc = tid; cc < 512; cc += 256) {
        int p = cc >> 2, k = cc & 3;
        const float* s = &lds[p * 35 + k * 8];
        uint4 o;
        o.x = pack2(s[0], s[1]); o.y = pack2(s[2], s[3]);
        o.z = pack2(s[4], s[5]); o.w = pack2(s[6], s[7]);
        ((uint4*)rowp)[4 + cc] = o;
    }
    if (tid < 4)       ((uint4*)rowp)[tid] = zz;
    else if (tid < 8)  ((uint4*)rowp)[129 * 4 + tid - 4] = zz;
}

// -------- rolling-row conv helpers (identical to R10) -----------------------
#define LOADROW(f0, f1, f2, R)                                                  \
    {                                                                           \
        const unsigned short* rp =                                              \
            xbase + ((size_t)(R) * 130 + w0) * 32 + laneoff;                    \
        f0 = *(const bf16x8*)(rp);                                              \
        f1 = *(const bf16x8*)(rp + 32);                                         \
        f2 = *(const bf16x8*)(rp + 64);                                         \
    }

#define MROW(f0, f1, f2, aA, aB, kh)                                            \
    {                                                                           \
        aA = __builtin_amdgcn_mfma_f32_16x16x32_bf16(wfr[2*((kh)*3+0)],   f0, aA, 0,0,0); \
        aB = __builtin_amdgcn_mfma_f32_16x16x32_bf16(wfr[2*((kh)*3+0)+1], f0, aB, 0,0,0); \
        aA = __builtin_amdgcn_mfma_f32_16x16x32_bf16(wfr[2*((kh)*3+1)],   f1, aA, 0,0,0); \
        aB = __builtin_amdgcn_mfma_f32_16x16x32_bf16(wfr[2*((kh)*3+1)+1], f1, aB, 0,0,0); \
        aA = __builtin_amdgcn_mfma_f32_16x16x32_bf16(wfr[2*((kh)*3+2)],   f2, aA, 0,0,0); \
        aB = __builtin_amdgcn_mfma_f32_16x16x32_bf16(wfr[2*((kh)*3+2)+1], f2, aB, 0,0,0); \
    }

#define CONV_PROLOGUE                                                           \
    bf16x8 wfr[18];                                                             \
    _Pragma("unroll")                                                           \
    for (int i = 0; i < 18; ++i)                                                \
        wfr[i] = *(const bf16x8*)(wfrag + (i * 64 + lane) * 8);                 \
    const unsigned short* xbase = xt + (size_t)n * 130 * 130 * 32;              \
    const int laneoff = l15 * 32 + lhi * 8;                                     \
    f32x4 zz4 = {0.f, 0.f, 0.f, 0.f};                                           \
    f32x4 a0A = zz4, a0B = zz4, a1A = zz4, a1B = zz4;                           \
    f32x4 a2A = zz4, a2B = zz4, a3A = zz4, a3B = zz4;                           \
    bf16x8 c0, c1, c2, n0, n1, n2;                                              \
    LOADROW(c0, c1, c2, h0);                                                    \
    LOADROW(n0, n1, n2, h0 + 1);

#define CONV_BODY(FIN)                                                          \
    MROW(c0, c1, c2, a0A, a0B, 0);                                              \
    LOADROW(c0, c1, c2, h0 + 2);                                                \
    MROW(n0, n1, n2, a0A, a0B, 1);                                              \
    MROW(n0, n1, n2, a1A, a1B, 0);                                              \
    LOADROW(n0, n1, n2, h0 + 3);                                                \
    MROW(c0, c1, c2, a0A, a0B, 2);                                              \
    MROW(c0, c1, c2, a1A, a1B, 1);                                              \
    MROW(c0, c1, c2, a2A, a2B, 0);                                              \
    FIN(a0A, a0B, 0);                                                           \
    LOADROW(c0, c1, c2, h0 + 4);                                                \
    MROW(n0, n1, n2, a1A, a1B, 2);                                              \
    MROW(n0, n1, n2, a2A, a2B, 1);                                              \
    MROW(n0, n1, n2, a3A, a3B, 0);                                              \
    FIN(a1A, a1B, 1);                                                           \
    LOADROW(n0, n1, n2, h0 + 5);                                                \
    MROW(c0, c1, c2, a2A, a2B, 2);                                              \
    MROW(c0, c1, c2, a3A, a3B, 1);                                              \
    FIN(a2A, a2B, 2);                                                           \
    MROW(n0, n1, n2, a3A, a3B, 2);                                              \
    FIN(a3A, a3B, 3);

// ---------------------------------------------------------------------------
// K2 conv_stats_store: conv -> (a) fp16 pre-BN output store to co,
// (b) per-block (sum,sumsq) -> atomicAdd into per-n acc copies.
// ---------------------------------------------------------------------------
__global__ __launch_bounds__(256) void conv_stats_store_kernel(
    const unsigned short* __restrict__ xt,
    const unsigned short* __restrict__ wfrag,
    float* __restrict__ acc, unsigned short* __restrict__ co)
{
    __shared__ float red[4][64];
    const int bid  = blockIdx.x;
    const int tid  = threadIdx.x;
    const int n    = (bid & 7) * 2 + ((bid >> 3) & 1);
    const int rest = bid >> 4;
    const int h0   = (rest & 31) * 4;
    const int wh   = rest >> 5;
    const int lane = tid & 63;
    const int wv   = tid >> 6;
    const int w0   = wh * 64 + wv * 16;
    const int l15  = lane & 15, lhi = lane >> 4;

    float s8[8], q8[8];
#pragma unroll
    for (int j = 0; j < 8; ++j) { s8[j] = 0.f; q8[j] = 0.f; }

    unsigned short* cb = co + (size_t)(n * FF + lhi * 4) * (HH * WWD)
                            + h0 * WWD + w0 + l15;

#define FIN_SS(aA, aB, hh)                                                      \
    {                                                                           \
        _Pragma("unroll")                                                       \
        for (int r = 0; r < 4; ++r) {                                           \
            float v0 = aA[r], v1 = aB[r];                                       \
            s8[r]     += v0;  q8[r]     += v0 * v0;                             \
            s8[4 + r] += v1;  q8[4 + r] += v1 * v1;                             \
            cb[(size_t)r * (HH * WWD) + (hh) * WWD]                    = f2h(v0); \
            cb[(size_t)r * (HH * WWD) + 16 * (HH * WWD) + (hh) * WWD]  = f2h(v1); \
        }                                                                       \
    }

    CONV_PROLOGUE
    CONV_BODY(FIN_SS)
#undef FIN_SS

#pragma unroll
    for (int m = 1; m < 16; m <<= 1) {
#pragma unroll
        for (int j = 0; j < 8; ++j) {
            s8[j] += __shfl_xor(s8[j], m, 64);
            q8[j] += __shfl_xor(q8[j], m, 64);
        }
    }
    if (l15 == 0) {
#pragma unroll
        for (int j = 0; j < 8; ++j) {
            int f = (j < 4) ? (lhi * 4 + j) : (16 + lhi * 4 + (j - 4));
            red[wv][f]      = s8[j];
            red[wv][32 + f] = q8[j];
        }
    }
    __syncthreads();
    if (tid < 64) {
        float v = red[0][tid] + red[1][tid] + red[2][tid] + red[3][tid];
        atomicAdd(&acc[n * 64 + tid], v);
    }
}

// ---------------------------------------------------------------------------
// K3 apply_stream: bns from acc; elementwise co(fp16) -> BN+ReLU -> out(fp32).
// 2048 blocks x 256 thr x 16 elems = 8,388,608 = NB*FF*HH*WWD exactly.
// ---------------------------------------------------------------------------
__global__ __launch_bounds__(256) void apply_stream_kernel(
    const unsigned short* __restrict__ co, const float* __restrict__ acc,
    const float* __restrict__ gamma, const float* __restrict__ beta,
    float* __restrict__ out)
{
    __shared__ float tot[64];
    __shared__ float bns[64];
    const int tid = threadIdx.x;

    if (tid < 64) {
        float s = 0.f;
#pragma unroll
        for (int k = 0; k < 16; ++k) s += acc[k * 64 + tid];
        tot[tid] = s;
    }
    __syncthreads();
    if (tid < 32) {
        float cnt  = (float)(NB * HH * WWD);
        float mean = tot[tid] / cnt;
        float var  = tot[32 + tid] / cnt - mean * mean;
        float sc   = gamma[tid] * rsqrtf(var + EPSV);
        bns[tid]      = sc;
        bns[32 + tid] = beta[tid] - mean * sc;
    }
    __syncthreads();

    const int i0 = (blockIdx.x * 256 + tid) * 16;
    const int f  = (i0 >> 14) & 31;          // HH*WWD = 16384 = 2^14
    const float sc = bns[f], sh = bns[32 + f];

    uint4 a = *(const uint4*)(co + i0);
    uint4 b = *(const uint4*)(co + i0 + 8);

    float v[16];
    v[0]  = h2f((unsigned short)(a.x & 0xffff)); v[1]  = h2f((unsigned short)(a.x >> 16));
    v[2]  = h2f((unsigned short)(a.y & 0xffff)); v[3]  = h2f((unsigned short)(a.y >> 16));
    v[4]  = h2f((unsigned short)(a.z & 0xffff)); v[5]  = h2f((unsigned short)(a.z >> 16));
    v[6]  = h2f((unsigned short)(a.w & 0xffff)); v[7]  = h2f((unsigned short)(a.w >> 16));
    v[8]  = h2f((unsigned short)(b.x & 0xffff)); v[9]  = h2f((unsigned short)(b.x >> 16));
    v[10] = h2f((unsigned short)(b.y & 0xffff)); v[11] = h2f((unsigned short)(b.y >> 16));
    v[12] = h2f((unsigned short)(b.z & 0xffff)); v[13] = h2f((unsigned short)(b.z >> 16));
    v[14] = h2f((unsigned short)(b.w & 0xffff)); v[15] = h2f((unsigned short)(b.w >> 16));

    f32x4* op = (f32x4*)(out + i0);
#pragma unroll
    for (int k = 0; k < 4; ++k) {
        f32x4 o;
        o.x = fmaxf(fmaf(v[4*k+0], sc, sh), 0.f);
        o.y = fmaxf(fmaf(v[4*k+1], sc, sh), 0.f);
        o.z = fmaxf(fmaf(v[4*k+2], sc, sh), 0.f);
        o.w = fmaxf(fmaf(v[4*k+3], sc, sh), 0.f);
        __builtin_nontemporal_store(o, op + k);
    }
}

// ---------------------------------------------------------------------------
// Mid-path K2/K3 (R10, proven) — used when ws fits xt but not co.
// ---------------------------------------------------------------------------
__global__ __launch_bounds__(256) void conv_stats_kernel(
    const unsigned short* __restrict__ xt,
    const unsigned short* __restrict__ wfrag,
    float* __restrict__ acc)
{
    __shared__ float red[4][64];
    const int bid  = blockIdx.x;
    const int tid  = threadIdx.x;
    const int n    = (bid & 7) * 2 + ((bid >> 3) & 1);
    const int rest = bid >> 4;
    const int h0   = (rest & 31) * 4;
    const int wh   = rest >> 5;
    const int lane = tid & 63;
    const int wv   = tid >> 6;
    const int w0   = wh * 64 + wv * 16;
    const int l15  = lane & 15, lhi = lane >> 4;

    float s8[8], q8[8];
#pragma unroll
    for (int j = 0; j < 8; ++j) { s8[j] = 0.f; q8[j] = 0.f; }

#define FIN_STATS(aA, aB, hh)                                                   \
    {                                                                           \
        _Pragma("unroll")                                                       \
        for (int r = 0; r < 4; ++r) {                                           \
            float v0 = aA[r], v1 = aB[r];                                       \
            s8[r]     += v0;  q8[r]     += v0 * v0;                             \
            s8[4 + r] += v1;  q8[4 + r] += v1 * v1;                             \
        }                                                                       \
    }

    CONV_PROLOGUE
    CONV_BODY(FIN_STATS)
#undef FIN_STATS

#pragma unroll
    for (int m = 1; m < 16; m <<= 1) {
#pragma unroll
        for (int j = 0; j < 8; ++j) {
            s8[j] += __shfl_xor(s8[j], m, 64);
            q8[j] += __shfl_xor(q8[j], m, 64);
        }
    }
    if (l15 == 0) {
#pragma unroll
        for (int j = 0; j < 8; ++j) {
            int f = (j < 4) ? (lhi * 4 + j) : (16 + lhi * 4 + (j - 4));
            red[wv][f]      = s8[j];
            red[wv][32 + f] = q8[j];
        }
    }
    __syncthreads();
    if (tid < 64) {
        float v = red[0][tid] + red[1][tid] + red[2][tid] + red[3][tid];
        atomicAdd(&acc[n * 64 + tid], v);
    }
}

__global__ __launch_bounds__(256) void conv_apply_kernel(
    const unsigned short* __restrict__ xt,
    const unsigned short* __restrict__ wfrag,
    const float* __restrict__ acc,
    const float* __restrict__ gamma, const float* __restrict__ beta,
    float* __restrict__ out)
{
    __shared__ float tot[64];
    __shared__ float bns[64];
    const int bid  = blockIdx.x;
    const int tid  = threadIdx.x;

    if (tid < 64) {
        float s = 0.f;
#pragma unroll
        for (int k = 0; k < 16; ++k) s += acc[k * 64 + tid];
        tot[tid] = s;
    }
    __syncthreads();
    if (tid < 32) {
        float cnt  = (float)(NB * HH * WWD);
        float mean = tot[tid] / cnt;
        float var  = tot[32 + tid] / cnt - mean * mean;
        float sc   = gamma[tid] * rsqrtf(var + EPSV);
        bns[tid]      = sc;
        bns[32 + tid] = beta[tid] - mean * sc;
    }

    const int n    = (bid & 7) * 2 + ((bid >> 3) & 1);
    const int rest = bid >> 4;
    const int h0   = (rest & 31) * 4;
    const int wh   = rest >> 5;
    const int lane = tid & 63;
    const int wv   = tid >> 6;
    const int w0   = wh * 64 + wv * 16;
    const int l15  = lane & 15, lhi = lane >> 4;

    __syncthreads();   // bns ready
    float sc0[4], sh0[4], sc1[4], sh1[4];
#pragma unroll
    for (int r = 0; r < 4; ++r) {
        int f0 = lhi * 4 + r, f1 = 16 + lhi * 4 + r;
        sc0[r] = bns[f0]; sh0[r] = bns[32 + f0];
        sc1[r] = bns[f1]; sh1[r] = bns[32 + f1];
    }

    float* ob = out + (size_t)(n * FF + lhi * 4) * (HH * WWD) + h0 * WWD + w0 + l15;

#define FIN_APPLY(aA, aB, hh)                                                   \
    {                                                                           \
        _Pragma("unroll")                                                       \
        for (int r = 0; r < 4; ++r) {                                           \
            __builtin_nontemporal_store(                                        \
                fmaxf(fmaf(aA[r], sc0[r], sh0[r]), 0.f),                        \
                ob + (size_t)r * (HH * WWD) + (hh) * WWD);                      \
            __builtin_nontemporal_store(                                        \
                fmaxf(fmaf(aB[r], sc1[r], sh1[r]), 0.f),                        \
                ob + (size_t)r * (HH * WWD) + 16 * (HH * WWD) + (hh) * WWD);    \
        }                                                                       \
    }

    CONV_PROLOGUE
    CONV_BODY(FIN_APPLY)
#undef FIN_APPLY
}

// ======================= fallback (fp32 VALU, small-ws) =====================
__global__ __launch_bounds__(256) void conv_kernel(
    const float* __restrict__ x, const float* __restrict__ Wall,
    const int* __restrict__ opidx, float* __restrict__ out)
{
    __shared__ float wlds[FF * 289];
    __shared__ float xlds[8 * 3 * 132];
    const int tid = threadIdx.x;
    const int h = blockIdx.x;
    const int n = blockIdx.y;
    for (int i = tid; i < FF * 288; i += 256) {
        int f = i / 288;
        int r = i - f * 288;
        int op = opidx[f];
        wlds[f * 289 + r] = Wall[(f * OPSN + op) * 288 + r];
    }
    const int f = tid & 31;
    const int wg = tid >> 5;
    const int w0 = wg << 4;
    float acc[16];
#pragma unroll
    for (int i = 0; i < 16; ++i) acc[i] = 0.f;
    const float* xn = x + (size_t)n * CINC * HH * WWD;
    for (int cc = 0; cc < 4; ++cc) {
        __syncthreads();
        for (int i = tid; i < 8 * 3 * 132; i += 256) {
            int c8 = i / (3 * 132);
            int rem = i - c8 * (3 * 132);
            int r = rem / 132;
            int wp = rem - r * 132;
            int hin = h + r - 1;
            int win = wp - 1;
            float v = 0.f;
            if ((unsigned)hin < HH && (unsigned)win < WWD)
                v = xn[((cc * 8 + c8) * HH + hin) * WWD + win];
            xlds[i] = v;
        }
        __syncthreads();
#pragma unroll
        for (int c8 = 0; c8 < 8; ++c8) {
            const int c = cc * 8 + c8;
            float wv[9];
#pragma unroll
            for (int k = 0; k < 9; ++k) wv[k] = wlds[f * 289 + c * 9 + k];
#pragma unroll
            for (int kh = 0; kh < 3; ++kh) {
                float xr[20];
                const float4* p = (const float4*)&xlds[(c8 * 3 + kh) * 132 + w0];
#pragma unroll
                for (int j = 0; j < 5; ++j) {
                    float4 v = p[j];
                    xr[j * 4 + 0] = v.x; xr[j * 4 + 1] = v.y;
                    xr[j * 4 + 2] = v.z; xr[j * 4 + 3] = v.w;
                }
#pragma unroll
                for (int kw = 0; kw < 3; ++kw) {
                    float wgt = wv[kh * 3 + kw];
#pragma unroll
                    for (int i = 0; i < 16; ++i)
                        acc[i] = fmaf(xr[i + kw], wgt, acc[i]);
                }
            }
        }
    }
    float* op_ = out + (((size_t)(n * FF + f) * HH + h) * WWD + w0);
#pragma unroll
    for (int j = 0; j < 4; ++j)
        ((float4*)op_)[j] = make_float4(acc[j * 4], acc[j * 4 + 1],
                                        acc[j * 4 + 2], acc[j * 4 + 3]);
}

__global__ __launch_bounds__(256) void stats_kernel(
    const float* __restrict__ out, const float* __restrict__ gamma,
    const float* __restrict__ beta, float* __restrict__ ws)
{
    __shared__ float ssum[256], ssq[256];
    const int f = blockIdx.x;
    const int tid = threadIdx.x;
    float s = 0.f, q = 0.f;
    for (int n = 0; n < NB; ++n) {
        const float4* p = (const float4*)(out + (size_t)(n * FF + f) * HH * WWD);
        for (int i = tid; i < HH * WWD / 4; i += 256) {
            float4 v = p[i];
            s += v.x + v.y + v.z + v.w;
            q += v.x * v.x + v.y * v.y + v.z * v.z + v.w * v.w;
        }
    }
    ssum[tid] = s; ssq[tid] = q;
    __syncthreads();
    for (int st = 128; st > 0; st >>= 1) {
        if (tid < st) { ssum[tid] += ssum[tid + st]; ssq[tid] += ssq[tid + st]; }
        __syncthreads();
    }
    if (tid == 0) {
        float cnt = (float)(NB * HH * WWD);
        float mean = ssum[0] / cnt;
        float var = ssq[0] / cnt - mean * mean;
        float sc = gamma[f] * rsqrtf(var + EPSV);
        ws[f] = sc;
        ws[FF + f] = beta[f] - mean * sc;
    }
}

__global__ __launch_bounds__(256) void apply_kernel(
    float* __restrict__ out, const float* __restrict__ bnp)
{
    const int total4 = NB * FF * HH * WWD / 4;
    for (int i = blockIdx.x * 256 + threadIdx.x; i < total4; i += gridDim.x * 256) {
        int f = (i >> 12) & 31;
        float sc = bnp[f], sh = bnp[FF + f];
        float4 v = ((const float4*)out)[i];
        v.x = fmaxf(fmaf(v.x, sc, sh), 0.f);
        v.y = fmaxf(fmaf(v.y, sc, sh), 0.f);
        v.z = fmaxf(fmaf(v.z, sc, sh), 0.f);
        v.w = fmaxf(fmaf(v.w, sc, sh), 0.f);
        ((float4*)out)[i] = v;
    }
}
// ===========================================================================

extern "C" void kernel_launch(void* const* d_in, const int* in_sizes, int n_in,
                              void* d_out, int out_size, void* d_ws, size_t ws_size,
                              hipStream_t stream) {
    const float* x     = (const float*)d_in[0];
    const float* Wall  = (const float*)d_in[1];
    const float* gamma = (const float*)d_in[2];
    const float* beta  = (const float*)d_in[3];
    const int*   opidx = (const int*)d_in[4];
    float* out = (float*)d_out;
    float* ws  = (float*)d_ws;

    if (ws_size >= WS_NEED2) {
        float*          acc   = ws;
        unsigned short* wfrag = (unsigned short*)((char*)d_ws + WS_WFRAG_BOFF);
        unsigned short* xt    = (unsigned short*)((char*)d_ws + WS_XT_BOFF);
        unsigned short* co    = (unsigned short*)((char*)d_ws + WS_CO_BOFF);

        transform_kernel<<<NB * 130 + 1, 256, 0, stream>>>(x, Wall, opidx, xt, wfrag, acc);
        conv_stats_store_kernel<<<1024, 256, 0, stream>>>(xt, wfrag, acc, co);
        apply_stream_kernel<<<2048, 256, 0, stream>>>(co, acc, gamma, beta, out);
    } else if (ws_size >= WS_NEED) {
        float*          acc   = ws;
        unsigned short* wfrag = (unsigned short*)((char*)d_ws + WS_WFRAG_BOFF);
        unsigned short* xt    = (unsigned short*)((char*)d_ws + WS_XT_BOFF);

        transform_kernel<<<NB * 130 + 1, 256, 0, stream>>>(x, Wall, opidx, xt, wfrag, acc);
        conv_stats_kernel<<<1024, 256, 0, stream>>>(xt, wfrag, acc);
        conv_apply_kernel<<<1024, 256, 0, stream>>>(xt, wfrag, acc, gamma, beta, out);
    } else {
        dim3 gridc(HH, NB);
        conv_kernel<<<gridc, 256, 0, stream>>>(x, Wall, opidx, out);
        stats_kernel<<<FF, 256, 0, stream>>>(out, gamma, beta, ws);
        apply_kernel<<<2048, 256, 0, stream>>>(out, ws);
    }
}

// Round 13
// 39.078 us; speedup vs baseline: 1.8834x; 1.4468x over previous
//
#include <hip/hip_runtime.h>

#define NB   16
#define CINC 32
#define HH   128
#define WWD  128
#define FF   32
#define OPSN 5
#define EPSV 1e-5f

// ws layout:
//   floats [0:1024)        acc: 16 copies x [sum[32] | sumsq[32]]  (zeroed by K1)
//   bytes  at 262400       wfrag (18 frags * 64 lanes * 8 bf16 = 18432 B)
//   bytes  at 280832       xt [16][130][130][32] bf16
#define WS_WFRAG_BOFF   262400
#define WS_XT_BOFF      280832
#define WS_NEED         (280832 + (size_t)16*130*130*32*2)

typedef __attribute__((ext_vector_type(8))) short bf16x8;
typedef __attribute__((ext_vector_type(4))) float f32x4;

__device__ __forceinline__ unsigned short f2bf(float f) {
    unsigned u = __builtin_bit_cast(unsigned, f);
    u += 0x7FFFu + ((u >> 16) & 1u);
    return (unsigned short)(u >> 16);
}
__device__ __forceinline__ unsigned pack2(float lo, float hi) {
    return (unsigned)f2bf(lo) | ((unsigned)f2bf(hi) << 16);
}

// ---------------------------------------------------------------------------
// K1 transform (identical to R10)
// ---------------------------------------------------------------------------
__global__ __launch_bounds__(256) void transform_kernel(
    const float* __restrict__ x, const float* __restrict__ Wall,
    const int* __restrict__ opidx, unsigned short* __restrict__ xt,
    unsigned short* __restrict__ wfrag, float* __restrict__ acc)
{
    __shared__ float lds[128 * 35];
    const int bid = blockIdx.x;
    const int tid = threadIdx.x;

    if (bid == NB * 130) {
        for (int i = tid; i < 1024; i += 256) acc[i] = 0.f;
        for (int idx = tid; idx < 9216; idx += 256) {
            int frag = idx >> 9;          // 0..17
            int lane = (idx >> 3) & 63;
            int j    = idx & 7;
            int s = frag >> 1, m = frag & 1;
            int kh = s / 3, kw = s - 3 * kh;
            int f = m * 16 + (lane & 15);
            int c = ((lane >> 4) << 3) + j;
            float v = Wall[((size_t)(f * OPSN + opidx[f]) * 288) + c * 9 + kh * 3 + kw];
            wfrag[idx] = f2bf(v);
        }
        return;
    }

    const int idx = bid >> 3;                      // 0..259
    const int n   = (bid & 7) * 2 + (idx / 130);   // XCD-aligned n
    const int hp  = idx % 130;

    unsigned short* rowp = xt + (size_t)(n * 130 + hp) * 130 * 32;
    uint4 zz = make_uint4(0, 0, 0, 0);

    if (hp == 0 || hp == 129) {
        for (int c = tid; c < 520; c += 256) ((uint4*)rowp)[c] = zz;
        return;
    }

    const int h = hp - 1;
    const float* xr = x + ((size_t)n * CINC * HH + h) * WWD;
    const int c  = tid >> 3;
    const int wq = tid & 7;
#pragma unroll
    for (int it = 0; it < 4; ++it) {
        int w4 = wq + it * 8;
        float4 v = ((const float4*)(xr + (size_t)c * (HH * WWD)))[w4];
        int w = w4 * 4;
        lds[(w + 0) * 35 + c] = v.x;
        lds[(w + 1) * 35 + c] = v.y;
        lds[(w + 2) * 35 + c] = v.z;
        lds[(w + 3) * 35 + c] = v.w;
    }
    __syncthreads();
    for (int cc = tid; cc < 512; cc += 256) {
        int p = cc >> 2, k = cc & 3;
        const float* s = &lds[p * 35 + k * 8];
        uint4 o;
        o.x = pack2(s[0], s[1]); o.y = pack2(s[2], s[3]);
        o.z = pack2(s[4], s[5]); o.w = pack2(s[6], s[7]);
        ((uint4*)rowp)[4 + cc] = o;
    }
    if (tid < 4)       ((uint4*)rowp)[tid] = zz;
    else if (tid < 8)  ((uint4*)rowp)[129 * 4 + tid - 4] = zz;
}

// -------- rolling-row conv helpers ------------------------------------------
#define LOADROW(f0, f1, f2, R)                                                  \
    {                                                                           \
        const unsigned short* rp =                                              \
            xbase + ((size_t)(R) * 130 + w0) * 32 + laneoff;                    \
        f0 = *(const bf16x8*)(rp);                                              \
        f1 = *(const bf16x8*)(rp + 32);                                         \
        f2 = *(const bf16x8*)(rp + 64);                                         \
    }

#define MROW(f0, f1, f2, aA, aB, kh)                                            \
    {                                                                           \
        aA = __builtin_amdgcn_mfma_f32_16x16x32_bf16(wfr[2*((kh)*3+0)],   f0, aA, 0,0,0); \
        aB = __builtin_amdgcn_mfma_f32_16x16x32_bf16(wfr[2*((kh)*3+0)+1], f0, aB, 0,0,0); \
        aA = __builtin_amdgcn_mfma_f32_16x16x32_bf16(wfr[2*((kh)*3+1)],   f1, aA, 0,0,0); \
        aB = __builtin_amdgcn_mfma_f32_16x16x32_bf16(wfr[2*((kh)*3+1)+1], f1, aB, 0,0,0); \
        aA = __builtin_amdgcn_mfma_f32_16x16x32_bf16(wfr[2*((kh)*3+2)],   f2, aA, 0,0,0); \
        aB = __builtin_amdgcn_mfma_f32_16x16x32_bf16(wfr[2*((kh)*3+2)+1], f2, aB, 0,0,0); \
    }

// One 4-row tile at base row H0. OBDECL lets the apply-variant bind `ob`.
#define CONV_TILE(FIN, H0, OBDECL)                                              \
    {                                                                           \
        OBDECL;                                                                 \
        f32x4 a0A = zz4, a0B = zz4, a1A = zz4, a1B = zz4;                       \
        f32x4 a2A = zz4, a2B = zz4, a3A = zz4, a3B = zz4;                       \
        bf16x8 c0, c1, c2, n0, n1, n2;                                          \
        LOADROW(c0, c1, c2, (H0));                                              \
        LOADROW(n0, n1, n2, (H0) + 1);                                          \
        MROW(c0, c1, c2, a0A, a0B, 0);                                          \
        LOADROW(c0, c1, c2, (H0) + 2);                                          \
        MROW(n0, n1, n2, a0A, a0B, 1);                                          \
        MROW(n0, n1, n2, a1A, a1B, 0);                                          \
        LOADROW(n0, n1, n2, (H0) + 3);                                          \
        MROW(c0, c1, c2, a0A, a0B, 2);                                          \
        MROW(c0, c1, c2, a1A, a1B, 1);                                          \
        MROW(c0, c1, c2, a2A, a2B, 0);                                          \
        FIN(a0A, a0B, 0);                                                       \
        LOADROW(c0, c1, c2, (H0) + 4);                                          \
        MROW(n0, n1, n2, a1A, a1B, 2);                                          \
        MROW(n0, n1, n2, a2A, a2B, 1);                                          \
        MROW(n0, n1, n2, a3A, a3B, 0);                                          \
        FIN(a1A, a1B, 1);                                                       \
        LOADROW(n0, n1, n2, (H0) + 5);                                          \
        MROW(c0, c1, c2, a2A, a2B, 2);                                          \
        MROW(c0, c1, c2, a3A, a3B, 1);                                          \
        FIN(a2A, a2B, 2);                                                       \
        MROW(n0, n1, n2, a3A, a3B, 2);                                          \
        FIN(a3A, a3B, 3);                                                       \
    }

#define NOOP_DECL (void)0

// Shared per-block decode for the 512-block conv kernels:
// n = XCD-aligned batch, hbase = 8-row group base, w0 = wave's 16-px column.
#define CONV_DECODE_512                                                         \
    const int bid  = blockIdx.x;                                                \
    const int tid  = threadIdx.x;                                               \
    const int n    = (bid & 7) * 2 + ((bid >> 3) & 1);                          \
    const int rest = bid >> 4;                  /* 0..31 */                     \
    const int hbase= (rest & 15) * 8;                                           \
    const int wh   = rest >> 4;                 /* 0..1  */                     \
    const int lane = tid & 63;                                                  \
    const int wv   = tid >> 6;                                                  \
    const int w0   = wh * 64 + wv * 16;                                         \
    const int l15  = lane & 15, lhi = lane >> 4;

#define WFR_LOAD                                                                \
    bf16x8 wfr[18];                                                             \
    _Pragma("unroll")                                                           \
    for (int i = 0; i < 18; ++i)                                                \
        wfr[i] = *(const bf16x8*)(wfrag + (i * 64 + lane) * 8);                 \
    const unsigned short* xbase = xt + (size_t)n * 130 * 130 * 32;              \
    const int laneoff = l15 * 32 + lhi * 8;                                     \
    f32x4 zz4 = {0.f, 0.f, 0.f, 0.f};

// ---------------------------------------------------------------------------
// K2 conv_stats: 512 blocks x 2 tiles (8 rows). One prologue + one reduction.
// __launch_bounds__(256,2): VGPR cap 256 so wfr stays register-resident.
// ---------------------------------------------------------------------------
__global__ __launch_bounds__(256, 2) void conv_stats_kernel(
    const unsigned short* __restrict__ xt,
    const unsigned short* __restrict__ wfrag,
    float* __restrict__ acc)
{
    __shared__ float red[4][64];
    CONV_DECODE_512
    WFR_LOAD

    float s8[8], q8[8];
#pragma unroll
    for (int j = 0; j < 8; ++j) { s8[j] = 0.f; q8[j] = 0.f; }

#define FIN_STATS(aA, aB, hh)                                                   \
    {                                                                           \
        _Pragma("unroll")                                                       \
        for (int r = 0; r < 4; ++r) {                                           \
            float v0 = aA[r], v1 = aB[r];                                       \
            s8[r]     += v0;  q8[r]     += v0 * v0;                             \
            s8[4 + r] += v1;  q8[4 + r] += v1 * v1;                             \
        }                                                                       \
    }

    CONV_TILE(FIN_STATS, hbase,     NOOP_DECL)
    CONV_TILE(FIN_STATS, hbase + 4, NOOP_DECL)
#undef FIN_STATS

    // butterfly over the 16 pixel-lanes (xor<16 keeps lhi group intact)
#pragma unroll
    for (int m = 1; m < 16; m <<= 1) {
#pragma unroll
        for (int j = 0; j < 8; ++j) {
            s8[j] += __shfl_xor(s8[j], m, 64);
            q8[j] += __shfl_xor(q8[j], m, 64);
        }
    }
    if (l15 == 0) {
#pragma unroll
        for (int j = 0; j < 8; ++j) {
            int f = (j < 4) ? (lhi * 4 + j) : (16 + lhi * 4 + (j - 4));
            red[wv][f]      = s8[j];
            red[wv][32 + f] = q8[j];
        }
    }
    __syncthreads();
    if (tid < 64) {
        float v = red[0][tid] + red[1][tid] + red[2][tid] + red[3][tid];
        atomicAdd(&acc[n * 64 + tid], v);
    }
}

// ---------------------------------------------------------------------------
// K3 conv_apply: 512 blocks x 2 tiles; bns prologue; fused BN+ReLU writes.
// ---------------------------------------------------------------------------
__global__ __launch_bounds__(256, 2) void conv_apply_kernel(
    const unsigned short* __restrict__ xt,
    const unsigned short* __restrict__ wfrag,
    const float* __restrict__ acc,
    const float* __restrict__ gamma, const float* __restrict__ beta,
    float* __restrict__ out)
{
    __shared__ float tot[64];
    __shared__ float bns[64];
    CONV_DECODE_512

    if (tid < 64) {
        float s = 0.f;
#pragma unroll
        for (int k = 0; k < 16; ++k) s += acc[k * 64 + tid];
        tot[tid] = s;
    }
    __syncthreads();
    if (tid < 32) {
        float cnt  = (float)(NB * HH * WWD);
        float mean = tot[tid] / cnt;
        float var  = tot[32 + tid] / cnt - mean * mean;
        float sc   = gamma[tid] * rsqrtf(var + EPSV);
        bns[tid]      = sc;
        bns[32 + tid] = beta[tid] - mean * sc;
    }
    __syncthreads();   // bns ready

    WFR_LOAD

    float sc0[4], sh0[4], sc1[4], sh1[4];
#pragma unroll
    for (int r = 0; r < 4; ++r) {
        int f0 = lhi * 4 + r, f1 = 16 + lhi * 4 + r;
        sc0[r] = bns[f0]; sh0[r] = bns[32 + f0];
        sc1[r] = bns[f1]; sh1[r] = bns[32 + f1];
    }

#define FIN_APPLY(aA, aB, hh)                                                   \
    {                                                                           \
        _Pragma("unroll")                                                       \
        for (int r = 0; r < 4; ++r) {                                           \
            __builtin_nontemporal_store(                                        \
                fmaxf(fmaf(aA[r], sc0[r], sh0[r]), 0.f),                        \
                ob + (size_t)r * (HH * WWD) + (hh) * WWD);                      \
            __builtin_nontemporal_store(                                        \
                fmaxf(fmaf(aB[r], sc1[r], sh1[r]), 0.f),                        \
                ob + (size_t)r * (HH * WWD) + 16 * (HH * WWD) + (hh) * WWD);    \
        }                                                                       \
    }

    CONV_TILE(FIN_APPLY, hbase,
        float* ob = out + (size_t)(n * FF + lhi * 4) * (HH * WWD)
                        + hbase * WWD + w0 + l15)
    CONV_TILE(FIN_APPLY, hbase + 4,
        float* ob = out + (size_t)(n * FF + lhi * 4) * (HH * WWD)
                        + (hbase + 4) * WWD + w0 + l15)
#undef FIN_APPLY
}

// ======================= fallback (fp32 VALU, small-ws) =====================
__global__ __launch_bounds__(256) void conv_kernel(
    const float* __restrict__ x, const float* __restrict__ Wall,
    const int* __restrict__ opidx, float* __restrict__ out)
{
    __shared__ float wlds[FF * 289];
    __shared__ float xlds[8 * 3 * 132];
    const int tid = threadIdx.x;
    const int h = blockIdx.x;
    const int n = blockIdx.y;
    for (int i = tid; i < FF * 288; i += 256) {
        int f = i / 288;
        int r = i - f * 288;
        int op = opidx[f];
        wlds[f * 289 + r] = Wall[(f * OPSN + op) * 288 + r];
    }
    const int f = tid & 31;
    const int wg = tid >> 5;
    const int w0 = wg << 4;
    float acc[16];
#pragma unroll
    for (int i = 0; i < 16; ++i) acc[i] = 0.f;
    const float* xn = x + (size_t)n * CINC * HH * WWD;
    for (int cc = 0; cc < 4; ++cc) {
        __syncthreads();
        for (int i = tid; i < 8 * 3 * 132; i += 256) {
            int c8 = i / (3 * 132);
            int rem = i - c8 * (3 * 132);
            int r = rem / 132;
            int wp = rem - r * 132;
            int hin = h + r - 1;
            int win = wp - 1;
            float v = 0.f;
            if ((unsigned)hin < HH && (unsigned)win < WWD)
                v = xn[((cc * 8 + c8) * HH + hin) * WWD + win];
            xlds[i] = v;
        }
        __syncthreads();
#pragma unroll
        for (int c8 = 0; c8 < 8; ++c8) {
            const int c = cc * 8 + c8;
            float wv[9];
#pragma unroll
            for (int k = 0; k < 9; ++k) wv[k] = wlds[f * 289 + c * 9 + k];
#pragma unroll
            for (int kh = 0; kh < 3; ++kh) {
                float xr[20];
                const float4* p = (const float4*)&xlds[(c8 * 3 + kh) * 132 + w0];
#pragma unroll
                for (int j = 0; j < 5; ++j) {
                    float4 v = p[j];
                    xr[j * 4 + 0] = v.x; xr[j * 4 + 1] = v.y;
                    xr[j * 4 + 2] = v.z; xr[j * 4 + 3] = v.w;
                }
#pragma unroll
                for (int kw = 0; kw < 3; ++kw) {
                    float wgt = wv[kh * 3 + kw];
#pragma unroll
                    for (int i = 0; i < 16; ++i)
                        acc[i] = fmaf(xr[i + kw], wgt, acc[i]);
                }
            }
        }
    }
    float* op_ = out + (((size_t)(n * FF + f) * HH + h) * WWD + w0);
#pragma unroll
    for (int j = 0; j < 4; ++j)
        ((float4*)op_)[j] = make_float4(acc[j * 4], acc[j * 4 + 1],
                                        acc[j * 4 + 2], acc[j * 4 + 3]);
}

__global__ __launch_bounds__(256) void stats_kernel(
    const float* __restrict__ out, const float* __restrict__ gamma,
    const float* __restrict__ beta, float* __restrict__ ws)
{
    __shared__ float ssum[256], ssq[256];
    const int f = blockIdx.x;
    const int tid = threadIdx.x;
    float s = 0.f, q = 0.f;
    for (int n = 0; n < NB; ++n) {
        const float4* p = (const float4*)(out + (size_t)(n * FF + f) * HH * WWD);
        for (int i = tid; i < HH * WWD / 4; i += 256) {
            float4 v = p[i];
            s += v.x + v.y + v.z + v.w;
            q += v.x * v.x + v.y * v.y + v.z * v.z + v.w * v.w;
        }
    }
    ssum[tid] = s; ssq[tid] = q;
    __syncthreads();
    for (int st = 128; st > 0; st >>= 1) {
        if (tid < st) { ssum[tid] += ssum[tid + st]; ssq[tid] += ssq[tid + st]; }
        __syncthreads();
    }
    if (tid == 0) {
        float cnt = (float)(NB * HH * WWD);
        float mean = ssum[0] / cnt;
        float var = ssq[0] / cnt - mean * mean;
        float sc = gamma[f] * rsqrtf(var + EPSV);
        ws[f] = sc;
        ws[FF + f] = beta[f] - mean * sc;
    }
}

__global__ __launch_bounds__(256) void apply_kernel(
    float* __restrict__ out, const float* __restrict__ bnp)
{
    const int total4 = NB * FF * HH * WWD / 4;
    for (int i = blockIdx.x * 256 + threadIdx.x; i < total4; i += gridDim.x * 256) {
        int f = (i >> 12) & 31;
        float sc = bnp[f], sh = bnp[FF + f];
        float4 v = ((const float4*)out)[i];
        v.x = fmaxf(fmaf(v.x, sc, sh), 0.f);
        v.y = fmaxf(fmaf(v.y, sc, sh), 0.f);
        v.z = fmaxf(fmaf(v.z, sc, sh), 0.f);
        v.w = fmaxf(fmaf(v.w, sc, sh), 0.f);
        ((float4*)out)[i] = v;
    }
}
// ===========================================================================

extern "C" void kernel_launch(void* const* d_in, const int* in_sizes, int n_in,
                              void* d_out, int out_size, void* d_ws, size_t ws_size,
                              hipStream_t stream) {
    const float* x     = (const float*)d_in[0];
    const float* Wall  = (const float*)d_in[1];
    const float* gamma = (const float*)d_in[2];
    const float* beta  = (const float*)d_in[3];
    const int*   opidx = (const int*)d_in[4];
    float* out = (float*)d_out;
    float* ws  = (float*)d_ws;

    if (ws_size >= WS_NEED) {
        float*          acc   = ws;
        unsigned short* wfrag = (unsigned short*)((char*)d_ws + WS_WFRAG_BOFF);
        unsigned short* xt    = (unsigned short*)((char*)d_ws + WS_XT_BOFF);

        transform_kernel<<<NB * 130 + 1, 256, 0, stream>>>(x, Wall, opidx, xt, wfrag, acc);
        conv_stats_kernel<<<512, 256, 0, stream>>>(xt, wfrag, acc);
        conv_apply_kernel<<<512, 256, 0, stream>>>(xt, wfrag, acc, gamma, beta, out);
    } else {
        dim3 gridc(HH, NB);
        conv_kernel<<<gridc, 256, 0, stream>>>(x, Wall, opidx, out);
        stats_kernel<<<FF, 256, 0, stream>>>(out, gamma, beta, ws);
        apply_kernel<<<2048, 256, 0, stream>>>(out, ws);
    }
}